// Round 4
// baseline (305.174 us; speedup 1.0000x reference)
//
#include <hip/hip_runtime.h>

typedef __bf16 bf16x8 __attribute__((ext_vector_type(8)));
typedef float f32x4 __attribute__((ext_vector_type(4)));
typedef unsigned int u32x4 __attribute__((ext_vector_type(4)));

typedef const void __attribute__((address_space(1)))* gas1;
typedef void __attribute__((address_space(3)))* las3;

__device__ __forceinline__ unsigned short f2bf(float f) {
  unsigned int u = __builtin_bit_cast(unsigned int, f);
  u += 0x7fffu + ((u >> 16) & 1u);   // RNE
  return (unsigned short)(u >> 16);
}
__device__ __forceinline__ float bf2f(unsigned short h) {
  unsigned int u = ((unsigned int)h) << 16;
  return __builtin_bit_cast(float, u);
}
__device__ __forceinline__ unsigned int pack2bf(float lo, float hi) {
  return (unsigned int)f2bf(lo) | ((unsigned int)f2bf(hi) << 16);
}
// truncating pack (P in [0,1])
__device__ __forceinline__ unsigned int packtr(float lo, float hi) {
  return __builtin_amdgcn_perm(__builtin_bit_cast(unsigned int, hi),
                               __builtin_bit_cast(unsigned int, lo), 0x07060302u);
}

// ---------------- x -> bf16 ----------------
__global__ __launch_bounds__(256) void cvt_f32_bf16(const float* __restrict__ src,
                                                    unsigned short* __restrict__ dst, int n4) {
  int i = blockIdx.x * 256 + threadIdx.x;
  if (i >= n4) return;
  float4 v = ((const float4*)src)[i];
  uint2 o;
  o.x = pack2bf(v.x, v.y);
  o.y = pack2bf(v.z, v.w);
  ((uint2*)dst)[i] = o;
}

// ---------------- W[K][N] fp32 -> Wt[N][K] bf16 ----------------
__global__ __launch_bounds__(256) void transpose_cvt(const float* __restrict__ src,
                                                     unsigned short* __restrict__ dst,
                                                     int R, int C) {
  __shared__ float tile[32][33];
  int c0 = blockIdx.x * 32, r0 = blockIdx.y * 32;
  int tx = threadIdx.x & 31, ty = threadIdx.x >> 5;
#pragma unroll
  for (int i = 0; i < 4; ++i)
    tile[ty + i * 8][tx] = src[(r0 + ty + i * 8) * C + c0 + tx];
  __syncthreads();
#pragma unroll
  for (int i = 0; i < 4; ++i)
    dst[(c0 + ty + i * 8) * R + r0 + tx] = f2bf(tile[tx][ty + i * 8]);
}

// ---------------- GEMM: 64x128 tile, 2 waves, BK=32, global_load_lds ----------------
__global__ __launch_bounds__(128) void gemm_bt3(const unsigned short* __restrict__ A,
                                                const unsigned short* __restrict__ Bt,
                                                void* __restrict__ Cout,
                                                int M, int N, int K, int outF32) {
  __shared__ __align__(16) unsigned short Als[64 * 32];
  __shared__ __align__(16) unsigned short Bls[128 * 32];
  const int tid = threadIdx.x;
  const int wave = tid >> 6, lane = tid & 63;
  const int lgrp = lane >> 4, lmod = lane & 15;
  const int wn = wave * 64;
  const int m0 = blockIdx.y * 64, n0 = blockIdx.x * 128;
  const int lr = lane >> 2, lc = (lane & 3) * 8;

  f32x4 acc[4][4] = {};

  for (int k0 = 0; k0 < K; k0 += 32) {
    __syncthreads();
#pragma unroll
    for (int it = 0; it < 2; ++it) {
      int idx = wave * 2 + it;
      __builtin_amdgcn_global_load_lds(
          (gas1)(const void*)&A[(size_t)(m0 + idx * 16 + lr) * K + k0 + lc],
          (las3)(void*)&Als[idx * 512], 16, 0, 0);
    }
#pragma unroll
    for (int it = 0; it < 4; ++it) {
      int idx = wave * 4 + it;
      __builtin_amdgcn_global_load_lds(
          (gas1)(const void*)&Bt[(size_t)(n0 + idx * 16 + lr) * K + k0 + lc],
          (las3)(void*)&Bls[idx * 512], 16, 0, 0);
    }
    __syncthreads();
    bf16x8 af[4], bfr[4];
#pragma unroll
    for (int mi = 0; mi < 4; ++mi)
      af[mi] = __builtin_bit_cast(bf16x8, *(const u32x4*)&Als[(mi * 16 + lmod) * 32 + lgrp * 8]);
#pragma unroll
    for (int ni = 0; ni < 4; ++ni)
      bfr[ni] = __builtin_bit_cast(bf16x8, *(const u32x4*)&Bls[(wn + ni * 16 + lmod) * 32 + lgrp * 8]);
#pragma unroll
    for (int mi = 0; mi < 4; ++mi)
#pragma unroll
      for (int ni = 0; ni < 4; ++ni)
        acc[mi][ni] = __builtin_amdgcn_mfma_f32_16x16x32_bf16(af[mi], bfr[ni], acc[mi][ni], 0, 0, 0);
  }

#pragma unroll
  for (int mi = 0; mi < 4; ++mi)
#pragma unroll
    for (int ni = 0; ni < 4; ++ni)
#pragma unroll
      for (int r = 0; r < 4; ++r) {
        int row = m0 + mi * 16 + lgrp * 4 + r;
        int col = n0 + wn + ni * 16 + lmod;
        float v = acc[mi][ni][r];
        if (outF32) ((float*)Cout)[(size_t)row * N + col] = v;
        else ((unsigned short*)Cout)[(size_t)row * N + col] = f2bf(v);
      }
}

// ---------------- RoPE + split Q/K (Q pre-scaled by 0.125*log2(e)) ----------------
__global__ __launch_bounds__(256) void rope_split(const unsigned short* __restrict__ qkv,
                                                  const float* __restrict__ sinT,
                                                  const float* __restrict__ cosT,
                                                  unsigned short* __restrict__ Qh,
                                                  unsigned short* __restrict__ Kh) {
  const float qscale = 0.18033688011112042f;
  int p = blockIdx.x * 256 + threadIdx.x;
  int s = p / 640, cp = p % 640;
  int col = cp * 2;
  unsigned int pair = *(const unsigned int*)&qkv[s * 1536 + col];
  float e = bf2f((unsigned short)(pair & 0xffff));
  float o = bf2f((unsigned short)(pair >> 16));
  if (col < 1024) {
    int h = col >> 6, d = col & 63, i = d >> 1;
    float sn = sinT[s * 32 + i], cs = cosT[s * 32 + i];
    unsigned int w = pack2bf((cs * e - sn * o) * qscale, (sn * e + cs * o) * qscale);
    *(unsigned int*)&Qh[(h * 4096 + s) * 64 + d] = w;
  } else {
    int c = col - 1024;
    int h = c >> 6, d = c & 63, i = d >> 1;
    float sn = sinT[s * 32 + i], cs = cosT[s * 32 + i];
    unsigned int w = pack2bf(cs * e - sn * o, sn * e + cs * o);
    *(unsigned int*)&Kh[(h * 4096 + s) * 64 + d] = w;
  }
}

// ---------------- V transpose ----------------
__global__ __launch_bounds__(256) void transpose_v(const unsigned short* __restrict__ qkv,
                                                   unsigned short* __restrict__ Vt) {
  __shared__ unsigned short tile[32][33];
  int h = blockIdx.z;
  int d0 = blockIdx.y * 32;
  int s0 = blockIdx.x * 32;
  int tx = threadIdx.x & 31, ty = threadIdx.x >> 5;
#pragma unroll
  for (int i = 0; i < 4; ++i)
    tile[ty + i * 8][tx] = qkv[(s0 + ty + i * 8) * 1536 + 1280 + h * 64 + d0 + tx];
  __syncthreads();
#pragma unroll
  for (int i = 0; i < 4; ++i)
    Vt[(h * 64 + d0 + ty + i * 8) * 4096 + s0 + tx] = tile[tx][ty + i * 8];
}

// ---------------- Flash attention, split-K segments ----------------
// grid (80,16): blockIdx.x -> descending-size segment r=79-bx; (qb, s) decoded from r.
// Segment covers chunks [c0, c0+cnt) of q-block qb (128 rows). Partial (O,m,l) out.
__global__ __launch_bounds__(256, 2) void attn4(const unsigned short* __restrict__ Qh,
                                                const unsigned short* __restrict__ Kh,
                                                const unsigned short* __restrict__ Vt,
                                                unsigned short* __restrict__ Opart,
                                                float2* __restrict__ ML) {
  __shared__ __align__(16) unsigned short Kls[128 * 68];
  __shared__ __align__(16) unsigned short Vls[64 * 136];
  const int head = blockIdx.y;
  const int r = 79 - blockIdx.x;          // descending work size
  int g, base;
  if (r < 8) { g = 0; base = 0; }
  else if (r < 24) { g = 1; base = 8; }
  else if (r < 48) { g = 2; base = 24; }
  else { g = 3; base = 48; }
  const int ns = g + 1;
  const int local = r - base;
  const int qb = 8 * g + local / ns;
  const int sseg = local % ns;
  const int nc = qb + 1;
  const int qq = nc / ns, rem = nc % ns;
  const int c0 = sseg * qq + (sseg < rem ? sseg : rem);
  const int cnt = qq + (sseg < rem ? 1 : 0);

  const int kvh = head >> 2;
  const int tid = threadIdx.x;
  const int wave = tid >> 6, lane = tid & 63;
  const int lgrp = lane >> 4, lmod = lane & 15;
  const int qbase = qb * 128;

  const unsigned short* Kg = Kh + (size_t)kvh * 4096 * 64;
  const unsigned short* Vg = Vt + (size_t)kvh * 64 * 4096;

  bf16x8 qf[2][2];
  int qrow[2];
#pragma unroll
  for (int qt = 0; qt < 2; ++qt) {
    qrow[qt] = qbase + wave * 32 + qt * 16 + lmod;
    const unsigned short* Qg = Qh + ((size_t)head * 4096 + qrow[qt]) * 64;
    qf[qt][0] = __builtin_bit_cast(bf16x8, *(const u32x4*)&Qg[lgrp * 8]);
    qf[qt][1] = __builtin_bit_cast(bf16x8, *(const u32x4*)&Qg[32 + lgrp * 8]);
  }

  const int kbase = (8 * (lmod >> 2) + (lmod & 3)) * 68 + lgrp * 8;
  const int vbase = lmod * 136 + lgrp * 8;

  f32x4 accO[2][4] = {};
  float m_i[2] = {-3e38f, -3e38f}, l_i[2] = {0.f, 0.f};

  for (int kci = 0; kci < cnt; ++kci) {
    const int kc = c0 + kci;
    const int kb = kc * 128;
    __syncthreads();
#pragma unroll
    for (int i = 0; i < 4; ++i) {
      int ii = tid + i * 256;
      int rr = ii >> 3, sg = (ii & 7) * 8;
      u32x4 dK = *(const u32x4*)&Kg[(size_t)(kb + rr) * 64 + sg];
      uint2* pd = (uint2*)&Kls[rr * 68 + sg];
      pd[0] = make_uint2(dK[0], dK[1]);
      pd[1] = make_uint2(dK[2], dK[3]);
    }
#pragma unroll
    for (int i = 0; i < 4; ++i) {
      int ii = tid + i * 256;
      int rr = ii >> 4, sg = (ii & 15) * 8;
      *(u32x4*)&Vls[rr * 136 + sg] = *(const u32x4*)&Vg[(size_t)rr * 4096 + kb + sg];
    }
    __syncthreads();

    f32x4 s[4][2][2];
#pragma unroll
    for (int gg = 0; gg < 4; ++gg)
#pragma unroll
      for (int t = 0; t < 2; ++t) {
        const unsigned short* ka = &Kls[kbase + (32 * gg + 4 * t) * 68];
        uint2 a0 = *(const uint2*)&ka[0];
        uint2 a1 = *(const uint2*)&ka[4];
        uint2 b0 = *(const uint2*)&ka[32];
        uint2 b1 = *(const uint2*)&ka[36];
        u32x4 lo = {a0.x, a0.y, a1.x, a1.y};
        u32x4 hi = {b0.x, b0.y, b1.x, b1.y};
        bf16x8 alo = __builtin_bit_cast(bf16x8, lo);
        bf16x8 ahi = __builtin_bit_cast(bf16x8, hi);
#pragma unroll
        for (int qt = 0; qt < 2; ++qt) {
          f32x4 z = {};
          z = __builtin_amdgcn_mfma_f32_16x16x32_bf16(alo, qf[qt][0], z, 0, 0, 0);
          z = __builtin_amdgcn_mfma_f32_16x16x32_bf16(ahi, qf[qt][1], z, 0, 0, 0);
          s[gg][t][qt] = z;
        }
      }

    if (kc == qb) {   // diagonal chunk: causal mask
#pragma unroll
      for (int qt = 0; qt < 2; ++qt)
#pragma unroll
        for (int gg = 0; gg < 4; ++gg)
#pragma unroll
          for (int t = 0; t < 2; ++t)
#pragma unroll
            for (int rr = 0; rr < 4; ++rr) {
              int key = kb + 32 * gg + 8 * lgrp + 4 * t + rr;
              if (key > qrow[qt]) s[gg][t][qt][rr] = -3e38f;
            }
    }

#pragma unroll
    for (int qt = 0; qt < 2; ++qt) {
      f32x4 v0 = s[0][0][qt], v1 = s[0][1][qt];
#pragma unroll
      for (int gg = 1; gg < 4; ++gg)
#pragma unroll
        for (int rr = 0; rr < 4; ++rr) {
          v0[rr] = fmaxf(v0[rr], s[gg][0][qt][rr]);
          v1[rr] = fmaxf(v1[rr], s[gg][1][qt][rr]);
        }
      float mx = fmaxf(fmaxf(fmaxf(v0[0], v0[1]), fmaxf(v0[2], v0[3])),
                       fmaxf(fmaxf(v1[0], v1[1]), fmaxf(v1[2], v1[3])));
      mx = fmaxf(mx, __shfl_xor(mx, 16, 64));
      mx = fmaxf(mx, __shfl_xor(mx, 32, 64));
      float mnew = fmaxf(m_i[qt], mx);
      float alpha = __builtin_amdgcn_exp2f(m_i[qt] - mnew);
      m_i[qt] = mnew;
      f32x4 su = {};
#pragma unroll
      for (int gg = 0; gg < 4; ++gg)
#pragma unroll
        for (int t = 0; t < 2; ++t)
#pragma unroll
          for (int rr = 0; rr < 4; ++rr) {
            float ev = __builtin_amdgcn_exp2f(s[gg][t][qt][rr] - mnew);
            s[gg][t][qt][rr] = ev;
            su[rr] += ev;
          }
      float rs = (su[0] + su[1]) + (su[2] + su[3]);
      rs += __shfl_xor(rs, 16, 64);
      rs += __shfl_xor(rs, 32, 64);
      l_i[qt] = l_i[qt] * alpha + rs;
#pragma unroll
      for (int dt = 0; dt < 4; ++dt)
#pragma unroll
        for (int rr = 0; rr < 4; ++rr) accO[qt][dt][rr] *= alpha;
    }

#pragma unroll
    for (int gg = 0; gg < 4; ++gg) {
      bf16x8 pf[2];
#pragma unroll
      for (int qt = 0; qt < 2; ++qt) {
        u32x4 pk;
        pk[0] = packtr(s[gg][0][qt][0], s[gg][0][qt][1]);
        pk[1] = packtr(s[gg][0][qt][2], s[gg][0][qt][3]);
        pk[2] = packtr(s[gg][1][qt][0], s[gg][1][qt][1]);
        pk[3] = packtr(s[gg][1][qt][2], s[gg][1][qt][3]);
        pf[qt] = __builtin_bit_cast(bf16x8, pk);
      }
#pragma unroll
      for (int dt = 0; dt < 4; ++dt) {
        bf16x8 vf = __builtin_bit_cast(bf16x8, *(const u32x4*)&Vls[vbase + dt * 2176 + 32 * gg]);
        accO[0][dt] = __builtin_amdgcn_mfma_f32_16x16x32_bf16(vf, pf[0], accO[0][dt], 0, 0, 0);
        accO[1][dt] = __builtin_amdgcn_mfma_f32_16x16x32_bf16(vf, pf[1], accO[1][dt], 0, 0, 0);
      }
    }
  }

  // write unnormalized partial O (bf16) + (m,l)
  const size_t obase = (size_t)(head * 80 + r) * 128;
#pragma unroll
  for (int qt = 0; qt < 2; ++qt) {
    int lrow = wave * 32 + qt * 16 + lmod;
#pragma unroll
    for (int dt = 0; dt < 4; ++dt) {
      uint2 o;
      o.x = pack2bf(accO[qt][dt][0], accO[qt][dt][1]);
      o.y = pack2bf(accO[qt][dt][2], accO[qt][dt][3]);
      *(uint2*)&Opart[(obase + lrow) * 64 + dt * 16 + lgrp * 4] = o;
    }
  }
  if (lane < 16) {
#pragma unroll
    for (int qt = 0; qt < 2; ++qt) {
      int lrow = wave * 32 + qt * 16 + lane;
      ML[obase + lrow] = make_float2(m_i[qt], l_i[qt]);
    }
  }
}

// ---------------- combine partials -> ctx (bf16) ----------------
__global__ __launch_bounds__(256) void attn_combine(const unsigned short* __restrict__ Opart,
                                                    const float2* __restrict__ ML,
                                                    unsigned short* __restrict__ ctx) {
  const int qb = blockIdx.x, head = blockIdx.y;
  const int g = qb >> 3;
  const int ns = g + 1;
  const int sbase = 4 * g * (g + 1) + (qb - 8 * g) * (g + 1);
  const int tid = threadIdx.x;
  const int d8 = (tid & 7) * 8;
#pragma unroll
  for (int pass = 0; pass < 4; ++pass) {
    int row = (tid >> 3) + pass * 32;
    float M = -3e38f;
    float2 mls[4];
    for (int s = 0; s < ns; ++s) {
      mls[s] = ML[(size_t)(head * 80 + sbase + s) * 128 + row];
      M = fmaxf(M, mls[s].x);
    }
    float w[4], ltot = 0.f;
    for (int s = 0; s < ns; ++s) {
      w[s] = __builtin_amdgcn_exp2f(mls[s].x - M);
      ltot += w[s] * mls[s].y;
    }
    float inv = 1.f / ltot;
    float acc[8] = {};
    for (int s = 0; s < ns; ++s) {
      u32x4 pv = *(const u32x4*)&Opart[((size_t)(head * 80 + sbase + s) * 128 + row) * 64 + d8];
      float ws = w[s];
#pragma unroll
      for (int j = 0; j < 4; ++j) {
        unsigned int word = pv[j];
        acc[2 * j]     += ws * bf2f((unsigned short)(word & 0xffff));
        acc[2 * j + 1] += ws * bf2f((unsigned short)(word >> 16));
      }
    }
    u32x4 o;
#pragma unroll
    for (int j = 0; j < 4; ++j)
      o[j] = pack2bf(acc[2 * j] * inv, acc[2 * j + 1] * inv);
    *(u32x4*)&ctx[(size_t)(qb * 128 + row) * 1024 + head * 64 + d8] = o;
  }
}

extern "C" void kernel_launch(void* const* d_in, const int* in_sizes, int n_in,
                              void* d_out, int out_size, void* d_ws, size_t ws_size,
                              hipStream_t stream) {
  const float* x    = (const float*)d_in[0];
  const float* wq   = (const float*)d_in[3];
  const float* wk   = (const float*)d_in[4];
  const float* wv   = (const float*)d_in[5];
  const float* wo   = (const float*)d_in[6];
  const float* sinT = (const float*)d_in[7];
  const float* cosT = (const float*)d_in[8];

  unsigned short* ws    = (unsigned short*)d_ws;
  unsigned short* xb    = ws;                          // 4M us
  unsigned short* wtqkv = xb + 4096 * 1024;            // 1.5M us
  unsigned short* qkv   = wtqkv + 1536 * 1024;         // 6M us
  unsigned short* Qh    = qkv + 4096 * 1536;           // 4M us
  unsigned short* Kh    = Qh + 16 * 4096 * 64;         // 1M us
  unsigned short* Vt    = Kh + 4 * 4096 * 64;          // 1M us
  unsigned short* ctx   = Vt + 4 * 64 * 4096;          // 4M us
  unsigned short* wot   = ctx + 4096 * 1024;           // 1M us (must survive attn)
  // partials alias dead xb/wtqkv/qkv region (dead before attn4 runs)
  unsigned short* Opart = ws;                          // 16*80*128*64 = 10.49M us
  float2*         ML    = (float2*)(ws + 16 * 80 * 128 * 64);  // 160K float2
  float* out = (float*)d_out;

  cvt_f32_bf16<<<4096, 256, 0, stream>>>(x, xb, 4096 * 1024 / 4);
  transpose_cvt<<<dim3(32, 32), 256, 0, stream>>>(wq, wtqkv, 1024, 1024);
  transpose_cvt<<<dim3(8, 32), 256, 0, stream>>>(wk, wtqkv + 1024 * 1024, 1024, 256);
  transpose_cvt<<<dim3(8, 32), 256, 0, stream>>>(wv, wtqkv + 1280 * 1024, 1024, 256);
  transpose_cvt<<<dim3(32, 32), 256, 0, stream>>>(wo, wot, 1024, 1024);

  gemm_bt3<<<dim3(12, 64), 128, 0, stream>>>(xb, wtqkv, qkv, 4096, 1536, 1024, 0);

  rope_split<<<10240, 256, 0, stream>>>(qkv, sinT, cosT, Qh, Kh);
  transpose_v<<<dim3(128, 2, 4), 256, 0, stream>>>(qkv, Vt);

  attn4<<<dim3(80, 16), 256, 0, stream>>>(Qh, Kh, Vt, Opart, ML);
  attn_combine<<<dim3(32, 16), 256, 0, stream>>>(Opart, ML, ctx);

  gemm_bt3<<<dim3(8, 64), 128, 0, stream>>>(ctx, wot, out, 4096, 1024, 1024, 1);
}

// Round 6
// 258.051 us; speedup vs baseline: 1.1826x; 1.1826x over previous
//
#include <hip/hip_runtime.h>

typedef __bf16 bf16x8 __attribute__((ext_vector_type(8)));
typedef float f32x4 __attribute__((ext_vector_type(4)));
typedef unsigned int u32x4 __attribute__((ext_vector_type(4)));

typedef const void __attribute__((address_space(1)))* gas1;
typedef void __attribute__((address_space(3)))* las3;

__device__ __forceinline__ unsigned short f2bf(float f) {
  unsigned int u = __builtin_bit_cast(unsigned int, f);
  u += 0x7fffu + ((u >> 16) & 1u);   // RNE
  return (unsigned short)(u >> 16);
}
__device__ __forceinline__ float bf2f(unsigned short h) {
  unsigned int u = ((unsigned int)h) << 16;
  return __builtin_bit_cast(float, u);
}
__device__ __forceinline__ unsigned int pack2bf(float lo, float hi) {
  return (unsigned int)f2bf(lo) | ((unsigned int)f2bf(hi) << 16);
}
// truncating pack (P in [0,1])
__device__ __forceinline__ unsigned int packtr(float lo, float hi) {
  return __builtin_amdgcn_perm(__builtin_bit_cast(unsigned int, hi),
                               __builtin_bit_cast(unsigned int, lo), 0x07060302u);
}

// ---------------- fused prep: x->bf16 + 4 weight transposes ----------------
// grid 6656: [0,4096) cvt x (1M float4); [4096,5120) wq^T; [5120,5376) wk^T;
// [5376,5632) wv^T; [5632,6656) wo^T.
__global__ __launch_bounds__(256) void prep(const float* __restrict__ x,
                                            const float* __restrict__ wq,
                                            const float* __restrict__ wk,
                                            const float* __restrict__ wv,
                                            const float* __restrict__ wo,
                                            unsigned short* __restrict__ xb,
                                            unsigned short* __restrict__ wtqkv,
                                            unsigned short* __restrict__ wot) {
  __shared__ float tile[32][33];
  const int b = blockIdx.x;
  const int tid = threadIdx.x;
  if (b < 4096) {
    int i = b * 256 + tid;
    float4 v = ((const float4*)x)[i];
    uint2 o;
    o.x = pack2bf(v.x, v.y);
    o.y = pack2bf(v.z, v.w);
    ((uint2*)xb)[i] = o;
    return;
  }
  const float* src;
  unsigned short* dst;
  int R, C, t;
  if (b < 5120)      { t = b - 4096; src = wq; dst = wtqkv;               R = 1024; C = 1024; }
  else if (b < 5376) { t = b - 5120; src = wk; dst = wtqkv + 1024 * 1024; R = 1024; C = 256; }
  else if (b < 5632) { t = b - 5376; src = wv; dst = wtqkv + 1280 * 1024; R = 1024; C = 256; }
  else               { t = b - 5632; src = wo; dst = wot;                 R = 1024; C = 1024; }
  const int ntc = C >> 5;
  const int c0 = (t % ntc) * 32, r0 = (t / ntc) * 32;
  const int tx = tid & 31, ty = tid >> 5;
#pragma unroll
  for (int i = 0; i < 4; ++i)
    tile[ty + i * 8][tx] = src[(r0 + ty + i * 8) * C + c0 + tx];
  __syncthreads();
#pragma unroll
  for (int i = 0; i < 4; ++i)
    dst[(c0 + ty + i * 8) * R + r0 + tx] = f2bf(tile[tx][ty + i * 8]);
}

// ---------------- GEMM (R3 known-good): 128x128, 4 waves, BK=32, global_load_lds ------
__global__ __launch_bounds__(256, 2) void gemm_bt2(const unsigned short* __restrict__ A,
                                                   const unsigned short* __restrict__ Bt,
                                                   void* __restrict__ Cout,
                                                   int M, int N, int K, int outF32) {
  __shared__ __align__(16) unsigned short Als[128 * 32];
  __shared__ __align__(16) unsigned short Bls[128 * 32];
  const int tid = threadIdx.x;
  const int wave = tid >> 6, lane = tid & 63;
  const int lgrp = lane >> 4, lmod = lane & 15;
  const int wm = (wave & 1) * 64, wn = (wave >> 1) * 64;
  const int m0 = blockIdx.y * 128, n0 = blockIdx.x * 128;

  f32x4 acc[4][4] = {};

  for (int k0 = 0; k0 < K; k0 += 32) {
    __syncthreads();
#pragma unroll
    for (int it = 0; it < 2; ++it) {
      int idx = tid + it * 256;
      int rr = idx >> 2, cc = (idx & 3) * 8;
      __builtin_amdgcn_global_load_lds((gas1)(const void*)&A[(size_t)(m0 + rr) * K + k0 + cc],
                                       (las3)(void*)&Als[(it * 256 + wave * 64) * 8], 16, 0, 0);
      __builtin_amdgcn_global_load_lds((gas1)(const void*)&Bt[(size_t)(n0 + rr) * K + k0 + cc],
                                       (las3)(void*)&Bls[(it * 256 + wave * 64) * 8], 16, 0, 0);
    }
    __syncthreads();
    bf16x8 af[4], bfr[4];
#pragma unroll
    for (int mi = 0; mi < 4; ++mi)
      af[mi] = __builtin_bit_cast(bf16x8, *(const u32x4*)&Als[(wm + mi * 16 + lmod) * 32 + lgrp * 8]);
#pragma unroll
    for (int ni = 0; ni < 4; ++ni)
      bfr[ni] = __builtin_bit_cast(bf16x8, *(const u32x4*)&Bls[(wn + ni * 16 + lmod) * 32 + lgrp * 8]);
#pragma unroll
    for (int mi = 0; mi < 4; ++mi)
#pragma unroll
      for (int ni = 0; ni < 4; ++ni)
        acc[mi][ni] = __builtin_amdgcn_mfma_f32_16x16x32_bf16(af[mi], bfr[ni], acc[mi][ni], 0, 0, 0);
  }

#pragma unroll
  for (int mi = 0; mi < 4; ++mi)
#pragma unroll
    for (int ni = 0; ni < 4; ++ni)
#pragma unroll
      for (int r = 0; r < 4; ++r) {
        int row = m0 + wm + mi * 16 + lgrp * 4 + r;
        int col = n0 + wn + ni * 16 + lmod;
        float v = acc[mi][ni][r];
        if (outF32) ((float*)Cout)[(size_t)row * N + col] = v;
        else ((unsigned short*)Cout)[(size_t)row * N + col] = f2bf(v);
      }
}

// ---------------- fused RoPE(Q,K) + V transpose ----------------
// grid 6144: [0,5120) rope (2 pairs/thread); [5120,6144) transpose_v tiles.
__global__ __launch_bounds__(256) void rope_vt(const unsigned short* __restrict__ qkv,
                                               const float* __restrict__ sinT,
                                               const float* __restrict__ cosT,
                                               unsigned short* __restrict__ Qh,
                                               unsigned short* __restrict__ Kh,
                                               unsigned short* __restrict__ Vt) {
  __shared__ unsigned short tile[32][33];
  const int b = blockIdx.x;
  const int tid = threadIdx.x;
  if (b < 5120) {
    const float qscale = 0.18033688011112042f;   // 0.125 * log2(e)
    int u = b * 256 + tid;                        // 4096 rows x 320 units
    int s = u / 320, cu = u % 320;
    int col = cu * 4;                             // 4 cols = 2 rope pairs
    uint2 pr = *(const uint2*)&qkv[s * 1536 + col];
    float e0 = bf2f((unsigned short)(pr.x & 0xffff));
    float o0 = bf2f((unsigned short)(pr.x >> 16));
    float e1 = bf2f((unsigned short)(pr.y & 0xffff));
    float o1 = bf2f((unsigned short)(pr.y >> 16));
    if (col < 1024) {
      int h = col >> 6, d = col & 63, i0 = d >> 1;
      float sn0 = sinT[s * 32 + i0], cs0 = cosT[s * 32 + i0];
      float sn1 = sinT[s * 32 + i0 + 1], cs1 = cosT[s * 32 + i0 + 1];
      uint2 w;
      w.x = pack2bf((cs0 * e0 - sn0 * o0) * qscale, (sn0 * e0 + cs0 * o0) * qscale);
      w.y = pack2bf((cs1 * e1 - sn1 * o1) * qscale, (sn1 * e1 + cs1 * o1) * qscale);
      *(uint2*)&Qh[(h * 4096 + s) * 64 + d] = w;
    } else {
      int c = col - 1024;
      int h = c >> 6, d = c & 63, i0 = d >> 1;
      float sn0 = sinT[s * 32 + i0], cs0 = cosT[s * 32 + i0];
      float sn1 = sinT[s * 32 + i0 + 1], cs1 = cosT[s * 32 + i0 + 1];
      uint2 w;
      w.x = pack2bf(cs0 * e0 - sn0 * o0, sn0 * e0 + cs0 * o0);
      w.y = pack2bf(cs1 * e1 - sn1 * o1, sn1 * e1 + cs1 * o1);
      *(uint2*)&Kh[(h * 4096 + s) * 64 + d] = w;
    }
    return;
  }
  int t = b - 5120;                 // 4 heads x (2 d-tiles x 128 s-tiles)
  int h = t >> 8, rem = t & 255;
  int d0 = (rem >> 7) * 32, s0 = (rem & 127) * 32;
  int tx = tid & 31, ty = tid >> 5;
#pragma unroll
  for (int i = 0; i < 4; ++i)
    tile[ty + i * 8][tx] = qkv[(s0 + ty + i * 8) * 1536 + 1280 + h * 64 + d0 + tx];
  __syncthreads();
#pragma unroll
  for (int i = 0; i < 4; ++i)
    Vt[(h * 64 + d0 + ty + i * 8) * 4096 + s0 + tx] = tile[tx][ty + i * 8];
}

// ---------------- Flash attention, S^T formulation, q=32/wave (R3 verbatim) ----------
__global__ __launch_bounds__(256, 2) void attn3(const unsigned short* __restrict__ Qh,
                                                const unsigned short* __restrict__ Kh,
                                                const unsigned short* __restrict__ Vt,
                                                unsigned short* __restrict__ ctx) {
  __shared__ __align__(16) unsigned short Kls[128 * 68];   // [key][d], stride 68
  __shared__ __align__(16) unsigned short Vls[64 * 136];   // [d][key], stride 136
  const int bx = blockIdx.x;
  const int head = bx & 15;
  const int qidx = bx >> 4;
  const int qb = (qidx < 16) ? (31 - qidx) : (qidx - 16);
  const int kvh = head >> 2;
  const int tid = threadIdx.x;
  const int wave = tid >> 6, lane = tid & 63;
  const int lgrp = lane >> 4, lmod = lane & 15;
  const int qbase = qb * 128;

  const unsigned short* Kg = Kh + (size_t)kvh * 4096 * 64;
  const unsigned short* Vg = Vt + (size_t)kvh * 64 * 4096;

  bf16x8 qf[2][2];
  int qrow[2];
#pragma unroll
  for (int qt = 0; qt < 2; ++qt) {
    qrow[qt] = qbase + wave * 32 + qt * 16 + lmod;
    const unsigned short* Qg = Qh + ((size_t)head * 4096 + qrow[qt]) * 64;
    qf[qt][0] = __builtin_bit_cast(bf16x8, *(const u32x4*)&Qg[lgrp * 8]);
    qf[qt][1] = __builtin_bit_cast(bf16x8, *(const u32x4*)&Qg[32 + lgrp * 8]);
  }

  const int kbase = (8 * (lmod >> 2) + (lmod & 3)) * 68 + lgrp * 8;
  const int vbase = lmod * 136 + lgrp * 8;

  f32x4 accO[2][4] = {};
  float m_i[2] = {-3e38f, -3e38f}, l_i[2] = {0.f, 0.f};

  for (int kc = 0; kc <= qb; ++kc) {
    const int kb = kc * 128;
    __syncthreads();
#pragma unroll
    for (int i = 0; i < 4; ++i) {
      int ii = tid + i * 256;
      int r = ii >> 3, sg = (ii & 7) * 8;
      u32x4 dK = *(const u32x4*)&Kg[(size_t)(kb + r) * 64 + sg];
      uint2* pd = (uint2*)&Kls[r * 68 + sg];
      pd[0] = make_uint2(dK[0], dK[1]);
      pd[1] = make_uint2(dK[2], dK[3]);
    }
#pragma unroll
    for (int i = 0; i < 4; ++i) {
      int ii = tid + i * 256;
      int r = ii >> 4, sg = (ii & 15) * 8;
      *(u32x4*)&Vls[r * 136 + sg] = *(const u32x4*)&Vg[(size_t)r * 4096 + kb + sg];
    }
    __syncthreads();

    f32x4 s[4][2][2];
#pragma unroll
    for (int g = 0; g < 4; ++g)
#pragma unroll
      for (int t = 0; t < 2; ++t) {
        const unsigned short* ka = &Kls[kbase + (32 * g + 4 * t) * 68];
        uint2 a0 = *(const uint2*)&ka[0];
        uint2 a1 = *(const uint2*)&ka[4];
        uint2 b0 = *(const uint2*)&ka[32];
        uint2 b1 = *(const uint2*)&ka[36];
        u32x4 lo = {a0.x, a0.y, a1.x, a1.y};
        u32x4 hi = {b0.x, b0.y, b1.x, b1.y};
        bf16x8 alo = __builtin_bit_cast(bf16x8, lo);
        bf16x8 ahi = __builtin_bit_cast(bf16x8, hi);
#pragma unroll
        for (int qt = 0; qt < 2; ++qt) {
          f32x4 z = {};
          z = __builtin_amdgcn_mfma_f32_16x16x32_bf16(alo, qf[qt][0], z, 0, 0, 0);
          z = __builtin_amdgcn_mfma_f32_16x16x32_bf16(ahi, qf[qt][1], z, 0, 0, 0);
          s[g][t][qt] = z;
        }
      }

#pragma unroll
    for (int qt = 0; qt < 2; ++qt) {
      if (kb + 127 > qbase + wave * 32 + qt * 16) {
#pragma unroll
        for (int g = 0; g < 4; ++g)
#pragma unroll
          for (int t = 0; t < 2; ++t)
#pragma unroll
            for (int r = 0; r < 4; ++r) {
              int key = kb + 32 * g + 8 * lgrp + 4 * t + r;
              if (key > qrow[qt]) s[g][t][qt][r] = -3e38f;
            }
      }
    }

#pragma unroll
    for (int qt = 0; qt < 2; ++qt) {
      f32x4 v0 = s[0][0][qt], v1 = s[0][1][qt];
#pragma unroll
      for (int g = 1; g < 4; ++g)
#pragma unroll
        for (int r = 0; r < 4; ++r) {
          v0[r] = fmaxf(v0[r], s[g][0][qt][r]);
          v1[r] = fmaxf(v1[r], s[g][1][qt][r]);
        }
      float mx = fmaxf(fmaxf(fmaxf(v0[0], v0[1]), fmaxf(v0[2], v0[3])),
                       fmaxf(fmaxf(v1[0], v1[1]), fmaxf(v1[2], v1[3])));
      mx = fmaxf(mx, __shfl_xor(mx, 16, 64));
      mx = fmaxf(mx, __shfl_xor(mx, 32, 64));
      float mnew = fmaxf(m_i[qt], mx);
      float alpha = __builtin_amdgcn_exp2f(m_i[qt] - mnew);
      m_i[qt] = mnew;
      f32x4 su = {};
#pragma unroll
      for (int g = 0; g < 4; ++g)
#pragma unroll
        for (int t = 0; t < 2; ++t)
#pragma unroll
          for (int r = 0; r < 4; ++r) {
            float ev = __builtin_amdgcn_exp2f(s[g][t][qt][r] - mnew);
            s[g][t][qt][r] = ev;
            su[r] += ev;
          }
      float rs = (su[0] + su[1]) + (su[2] + su[3]);
      rs += __shfl_xor(rs, 16, 64);
      rs += __shfl_xor(rs, 32, 64);
      l_i[qt] = l_i[qt] * alpha + rs;
#pragma unroll
      for (int dt = 0; dt < 4; ++dt)
#pragma unroll
        for (int r = 0; r < 4; ++r) accO[qt][dt][r] *= alpha;
    }

#pragma unroll
    for (int g = 0; g < 4; ++g) {
      bf16x8 pf[2];
#pragma unroll
      for (int qt = 0; qt < 2; ++qt) {
        u32x4 pk;
        pk[0] = packtr(s[g][0][qt][0], s[g][0][qt][1]);
        pk[1] = packtr(s[g][0][qt][2], s[g][0][qt][3]);
        pk[2] = packtr(s[g][1][qt][0], s[g][1][qt][1]);
        pk[3] = packtr(s[g][1][qt][2], s[g][1][qt][3]);
        pf[qt] = __builtin_bit_cast(bf16x8, pk);
      }
#pragma unroll
      for (int dt = 0; dt < 4; ++dt) {
        bf16x8 vf = __builtin_bit_cast(bf16x8, *(const u32x4*)&Vls[vbase + dt * 2176 + 32 * g]);
        accO[0][dt] = __builtin_amdgcn_mfma_f32_16x16x32_bf16(vf, pf[0], accO[0][dt], 0, 0, 0);
        accO[1][dt] = __builtin_amdgcn_mfma_f32_16x16x32_bf16(vf, pf[1], accO[1][dt], 0, 0, 0);
      }
    }
  }

#pragma unroll
  for (int qt = 0; qt < 2; ++qt) {
    float inv = 1.f / l_i[qt];
#pragma unroll
    for (int dt = 0; dt < 4; ++dt) {
      uint2 o;
      o.x = pack2bf(accO[qt][dt][0] * inv, accO[qt][dt][1] * inv);
      o.y = pack2bf(accO[qt][dt][2] * inv, accO[qt][dt][3] * inv);
      *(uint2*)&ctx[(size_t)qrow[qt] * 1024 + head * 64 + dt * 16 + lgrp * 4] = o;
    }
  }
}

extern "C" void kernel_launch(void* const* d_in, const int* in_sizes, int n_in,
                              void* d_out, int out_size, void* d_ws, size_t ws_size,
                              hipStream_t stream) {
  const float* x    = (const float*)d_in[0];
  const float* wq   = (const float*)d_in[3];
  const float* wk   = (const float*)d_in[4];
  const float* wv   = (const float*)d_in[5];
  const float* wo   = (const float*)d_in[6];
  const float* sinT = (const float*)d_in[7];
  const float* cosT = (const float*)d_in[8];

  unsigned short* ws    = (unsigned short*)d_ws;
  unsigned short* xb    = ws;                          // 4096*1024
  unsigned short* wtqkv = xb + 4096 * 1024;            // 1536*1024
  unsigned short* wot   = wtqkv + 1536 * 1024;         // 1024*1024
  unsigned short* qkv   = wot + 1024 * 1024;           // 4096*1536
  unsigned short* Qh    = qkv + 4096 * 1536;           // 16*4096*64
  unsigned short* Kh    = Qh + 16 * 4096 * 64;         // 4*4096*64
  unsigned short* Vt    = Kh + 4 * 4096 * 64;          // 4*64*4096
  unsigned short* ctx   = Vt + 4 * 64 * 4096;          // 4096*1024
  float* out = (float*)d_out;

  prep<<<6656, 256, 0, stream>>>(x, wq, wk, wv, wo, xb, wtqkv, wot);
  gemm_bt2<<<dim3(12, 32), 256, 0, stream>>>(xb, wtqkv, qkv, 4096, 1536, 1024, 0);
  rope_vt<<<6144, 256, 0, stream>>>(qkv, sinT, cosT, Qh, Kh, Vt);
  attn3<<<dim3(512), 256, 0, stream>>>(Qh, Kh, Vt, ctx);
  gemm_bt2<<<dim3(8, 32), 256, 0, stream>>>(ctx, wot, out, 4096, 1024, 1024, 1);
}

// Round 7
// 250.961 us; speedup vs baseline: 1.2160x; 1.0282x over previous
//
#include <hip/hip_runtime.h>

typedef __bf16 bf16x8 __attribute__((ext_vector_type(8)));
typedef float f32x4 __attribute__((ext_vector_type(4)));
typedef unsigned int u32x4 __attribute__((ext_vector_type(4)));

typedef const void __attribute__((address_space(1)))* gas1;
typedef void __attribute__((address_space(3)))* las3;

__device__ __forceinline__ unsigned short f2bf(float f) {
  unsigned int u = __builtin_bit_cast(unsigned int, f);
  u += 0x7fffu + ((u >> 16) & 1u);   // RNE
  return (unsigned short)(u >> 16);
}
__device__ __forceinline__ float bf2f(unsigned short h) {
  unsigned int u = ((unsigned int)h) << 16;
  return __builtin_bit_cast(float, u);
}
__device__ __forceinline__ unsigned int pack2bf(float lo, float hi) {
  return (unsigned int)f2bf(lo) | ((unsigned int)f2bf(hi) << 16);
}
// truncating pack (P in [0,1])
__device__ __forceinline__ unsigned int packtr(float lo, float hi) {
  return __builtin_amdgcn_perm(__builtin_bit_cast(unsigned int, hi),
                               __builtin_bit_cast(unsigned int, lo), 0x07060302u);
}

// ---------------- fused prep: x->bf16 + 4 weight transposes ----------------
// grid 6656: [0,4096) cvt x; [4096,5120) wq^T; [5120,5376) wk^T; [5376,5632) wv^T;
// [5632,6656) wo^T.
__global__ __launch_bounds__(256) void prep(const float* __restrict__ x,
                                            const float* __restrict__ wq,
                                            const float* __restrict__ wk,
                                            const float* __restrict__ wv,
                                            const float* __restrict__ wo,
                                            unsigned short* __restrict__ xb,
                                            unsigned short* __restrict__ wtqkv,
                                            unsigned short* __restrict__ wot) {
  __shared__ float tile[32][33];
  const int b = blockIdx.x;
  const int tid = threadIdx.x;
  if (b < 4096) {
    int i = b * 256 + tid;
    float4 v = ((const float4*)x)[i];
    uint2 o;
    o.x = pack2bf(v.x, v.y);
    o.y = pack2bf(v.z, v.w);
    ((uint2*)xb)[i] = o;
    return;
  }
  const float* src;
  unsigned short* dst;
  int R, C, t;
  if (b < 5120)      { t = b - 4096; src = wq; dst = wtqkv;               R = 1024; C = 1024; }
  else if (b < 5376) { t = b - 5120; src = wk; dst = wtqkv + 1024 * 1024; R = 1024; C = 256; }
  else if (b < 5632) { t = b - 5376; src = wv; dst = wtqkv + 1280 * 1024; R = 1024; C = 256; }
  else               { t = b - 5632; src = wo; dst = wot;                 R = 1024; C = 1024; }
  const int ntc = C >> 5;
  const int c0 = (t % ntc) * 32, r0 = (t / ntc) * 32;
  const int tx = tid & 31, ty = tid >> 5;
#pragma unroll
  for (int i = 0; i < 4; ++i)
    tile[ty + i * 8][tx] = src[(r0 + ty + i * 8) * C + c0 + tx];
  __syncthreads();
#pragma unroll
  for (int i = 0; i < 4; ++i)
    dst[(c0 + ty + i * 8) * R + r0 + tx] = f2bf(tile[tx][ty + i * 8]);
}

// ---------------- QKV GEMM, BK=64 dual-buffer + fused RoPE/split/V^T epilogue ---------
// C = xb[4096x1024] @ wtqkv[1536x1024]^T. Tiles n 0..7 -> Q(rope,qscale), 8..9 -> K(rope),
// 10..11 -> V (transposed store). 128x128 tile, 4 waves.
__global__ __launch_bounds__(256, 2) void gemm_qkv(const unsigned short* __restrict__ A,
                                                   const unsigned short* __restrict__ Bt,
                                                   const float* __restrict__ sinT,
                                                   const float* __restrict__ cosT,
                                                   unsigned short* __restrict__ Qh,
                                                   unsigned short* __restrict__ Kh,
                                                   unsigned short* __restrict__ Vt) {
  __shared__ __align__(16) unsigned short Als[2][128 * 32];
  __shared__ __align__(16) unsigned short Bls[2][128 * 32];
  const int K = 1024;
  const int tid = threadIdx.x;
  const int wave = tid >> 6, lane = tid & 63;
  const int lgrp = lane >> 4, lmod = lane & 15;
  const int wm = (wave & 1) * 64, wn = (wave >> 1) * 64;
  const int m0 = blockIdx.y * 128, n0 = blockIdx.x * 128;

  f32x4 acc[4][4] = {};

  for (int k0 = 0; k0 < K; k0 += 64) {
    __syncthreads();
#pragma unroll
    for (int half = 0; half < 2; ++half) {
      int kk = k0 + half * 32;
#pragma unroll
      for (int it = 0; it < 2; ++it) {
        int idx = tid + it * 256;
        int rr = idx >> 2, cc = (idx & 3) * 8;
        __builtin_amdgcn_global_load_lds((gas1)(const void*)&A[(size_t)(m0 + rr) * K + kk + cc],
                                         (las3)(void*)&Als[half][(it * 256 + wave * 64) * 8], 16, 0, 0);
        __builtin_amdgcn_global_load_lds((gas1)(const void*)&Bt[(size_t)(n0 + rr) * K + kk + cc],
                                         (las3)(void*)&Bls[half][(it * 256 + wave * 64) * 8], 16, 0, 0);
      }
    }
    __syncthreads();
#pragma unroll
    for (int half = 0; half < 2; ++half) {
      bf16x8 af[4], bfr[4];
#pragma unroll
      for (int mi = 0; mi < 4; ++mi)
        af[mi] = __builtin_bit_cast(bf16x8, *(const u32x4*)&Als[half][(wm + mi * 16 + lmod) * 32 + lgrp * 8]);
#pragma unroll
      for (int ni = 0; ni < 4; ++ni)
        bfr[ni] = __builtin_bit_cast(bf16x8, *(const u32x4*)&Bls[half][(wn + ni * 16 + lmod) * 32 + lgrp * 8]);
#pragma unroll
      for (int mi = 0; mi < 4; ++mi)
#pragma unroll
        for (int ni = 0; ni < 4; ++ni)
          acc[mi][ni] = __builtin_amdgcn_mfma_f32_16x16x32_bf16(af[mi], bfr[ni], acc[mi][ni], 0, 0, 0);
    }
  }

  const int cbase = n0 + wn;           // multiple of 64
  if (cbase >= 1280) {
    // ---- V: transposed store, no rope ----
    const int kvh = (cbase - 1280) >> 6;
#pragma unroll
    for (int mi = 0; mi < 4; ++mi)
#pragma unroll
      for (int ni = 0; ni < 4; ++ni) {
        int d = ni * 16 + lmod;
        int s = m0 + wm + mi * 16 + lgrp * 4;
        uint2 o;
        o.x = pack2bf(acc[mi][ni][0], acc[mi][ni][1]);
        o.y = pack2bf(acc[mi][ni][2], acc[mi][ni][3]);
        *(uint2*)&Vt[((size_t)(kvh * 64 + d)) * 4096 + s] = o;
      }
    return;
  }

  // ---- Q/K: rope. Stage sin/cos[m0..m0+127][0..31] into dead Als/Bls ----
  __syncthreads();
  float* sinls = (float*)&Als[0][0];   // 128*32 f32 = 16 KB
  float* cosls = (float*)&Bls[0][0];
#pragma unroll
  for (int j = 0; j < 4; ++j) {
    int idx = tid + j * 256;
    int rr = idx >> 3, cc = (idx & 7) * 4;
    *(float4*)&sinls[rr * 32 + cc] = *(const float4*)&sinT[(size_t)(m0 + rr) * 32 + cc];
    *(float4*)&cosls[rr * 32 + cc] = *(const float4*)&cosT[(size_t)(m0 + rr) * 32 + cc];
  }
  __syncthreads();

  const float qscale = 0.18033688011112042f;   // 0.125 * log2(e)
  const bool isQ = (cbase < 1024);
  const int h = isQ ? (cbase >> 6) : ((cbase - 1024) >> 6);
  unsigned short* dstbase = isQ ? Qh : Kh;
  const bool evn = (lmod & 1) == 0;
#pragma unroll
  for (int mi = 0; mi < 4; ++mi)
#pragma unroll
    for (int ni = 0; ni < 4; ++ni) {
      int d = ni * 16 + lmod;
      int i = ni * 8 + (lmod >> 1);
#pragma unroll
      for (int r = 0; r < 4; ++r) {
        float v = acc[mi][ni][r];
        float p = __shfl_xor(v, 1, 64);
        int rl = wm + mi * 16 + lgrp * 4 + r;
        float sn = sinls[rl * 32 + i], cs = cosls[rl * 32 + i];
        float e = evn ? v : p, o = evn ? p : v;
        float outv = evn ? (cs * e - sn * o) : (sn * e + cs * o);
        if (isQ) outv *= qscale;
        dstbase[((size_t)h * 4096 + m0 + rl) * 64 + d] = f2bf(outv);
      }
    }
}

// ---------------- out-proj GEMM, BK=64 dual-buffer, f32 out ----------------
__global__ __launch_bounds__(256, 2) void gemm_out(const unsigned short* __restrict__ A,
                                                   const unsigned short* __restrict__ Bt,
                                                   float* __restrict__ Cout) {
  __shared__ __align__(16) unsigned short Als[2][128 * 32];
  __shared__ __align__(16) unsigned short Bls[2][128 * 32];
  const int K = 1024, N = 1024;
  const int tid = threadIdx.x;
  const int wave = tid >> 6, lane = tid & 63;
  const int lgrp = lane >> 4, lmod = lane & 15;
  const int wm = (wave & 1) * 64, wn = (wave >> 1) * 64;
  const int m0 = blockIdx.y * 128, n0 = blockIdx.x * 128;

  f32x4 acc[4][4] = {};

  for (int k0 = 0; k0 < K; k0 += 64) {
    __syncthreads();
#pragma unroll
    for (int half = 0; half < 2; ++half) {
      int kk = k0 + half * 32;
#pragma unroll
      for (int it = 0; it < 2; ++it) {
        int idx = tid + it * 256;
        int rr = idx >> 2, cc = (idx & 3) * 8;
        __builtin_amdgcn_global_load_lds((gas1)(const void*)&A[(size_t)(m0 + rr) * K + kk + cc],
                                         (las3)(void*)&Als[half][(it * 256 + wave * 64) * 8], 16, 0, 0);
        __builtin_amdgcn_global_load_lds((gas1)(const void*)&Bt[(size_t)(n0 + rr) * K + kk + cc],
                                         (las3)(void*)&Bls[half][(it * 256 + wave * 64) * 8], 16, 0, 0);
      }
    }
    __syncthreads();
#pragma unroll
    for (int half = 0; half < 2; ++half) {
      bf16x8 af[4], bfr[4];
#pragma unroll
      for (int mi = 0; mi < 4; ++mi)
        af[mi] = __builtin_bit_cast(bf16x8, *(const u32x4*)&Als[half][(wm + mi * 16 + lmod) * 32 + lgrp * 8]);
#pragma unroll
      for (int ni = 0; ni < 4; ++ni)
        bfr[ni] = __builtin_bit_cast(bf16x8, *(const u32x4*)&Bls[half][(wn + ni * 16 + lmod) * 32 + lgrp * 8]);
#pragma unroll
      for (int mi = 0; mi < 4; ++mi)
#pragma unroll
        for (int ni = 0; ni < 4; ++ni)
          acc[mi][ni] = __builtin_amdgcn_mfma_f32_16x16x32_bf16(af[mi], bfr[ni], acc[mi][ni], 0, 0, 0);
    }
  }

#pragma unroll
  for (int mi = 0; mi < 4; ++mi)
#pragma unroll
    for (int ni = 0; ni < 4; ++ni)
#pragma unroll
      for (int r = 0; r < 4; ++r) {
        int row = m0 + wm + mi * 16 + lgrp * 4 + r;
        int col = n0 + wn + ni * 16 + lmod;
        Cout[(size_t)row * N + col] = acc[mi][ni][r];
      }
}

// ---------------- Flash attention: S^T form, swizzled-b128 K frags ----------------
// K LDS: tiles (g,t) of 128 slots x 16B; slot sigma = h*64+lgrp*16+(m^(h*4+lgrp)).
// Write phases (fixed m, s8 varies) and read phases (m octet varies) both conflict-free.
__global__ __launch_bounds__(256, 2) void attn5(const unsigned short* __restrict__ Qh,
                                                const unsigned short* __restrict__ Kh,
                                                const unsigned short* __restrict__ Vt,
                                                unsigned short* __restrict__ ctx) {
  __shared__ __align__(16) unsigned short Kls[8 * 128 * 8];  // 16 KB
  __shared__ __align__(16) unsigned short Vls[64 * 136];     // [d][key], stride 136
  const int bx = blockIdx.x;
  const int head = bx & 15;
  const int qidx = bx >> 4;
  const int qb = (qidx < 16) ? (31 - qidx) : (qidx - 16);
  const int kvh = head >> 2;
  const int tid = threadIdx.x;
  const int wave = tid >> 6, lane = tid & 63;
  const int lgrp = lane >> 4, lmod = lane & 15;
  const int qbase = qb * 128;

  const unsigned short* Kg = Kh + (size_t)kvh * 4096 * 64;
  const unsigned short* Vg = Vt + (size_t)kvh * 64 * 4096;

  bf16x8 qf[2][2];
  int qrow[2];
#pragma unroll
  for (int qt = 0; qt < 2; ++qt) {
    qrow[qt] = qbase + wave * 32 + qt * 16 + lmod;
    const unsigned short* Qg = Qh + ((size_t)head * 4096 + qrow[qt]) * 64;
    qf[qt][0] = __builtin_bit_cast(bf16x8, *(const u32x4*)&Qg[lgrp * 8]);
    qf[qt][1] = __builtin_bit_cast(bf16x8, *(const u32x4*)&Qg[32 + lgrp * 8]);
  }

  // per-lane read offsets for the two k-halves (shorts)
  int krd[2];
#pragma unroll
  for (int h = 0; h < 2; ++h)
    krd[h] = (h * 64 + lgrp * 16 + (lmod ^ (h * 4 + lgrp))) * 8;
  const int vbase = lmod * 136 + lgrp * 8;

  f32x4 accO[2][4] = {};
  float m_i[2] = {-3e38f, -3e38f}, l_i[2] = {0.f, 0.f};

  for (int kc = 0; kc <= qb; ++kc) {
    const int kb = kc * 128;
    __syncthreads();
#pragma unroll
    for (int i = 0; i < 4; ++i) {
      int ii = tid + i * 256;
      int r = ii >> 3, s8 = ii & 7;
      u32x4 dK = *(const u32x4*)&Kg[(size_t)(kb + r) * 64 + s8 * 8];
      int g = r >> 5, r5 = r & 31;
      int t = (r5 >> 2) & 1;
      int m = ((r5 >> 3) << 2) | (r5 & 3);
      int sigma = ((s8 >> 2) << 6) | ((s8 & 3) << 4) | (m ^ s8);
      *(u32x4*)&Kls[(((g << 1) | t) << 10) + (sigma << 3)] = dK;
    }
#pragma unroll
    for (int i = 0; i < 4; ++i) {
      int ii = tid + i * 256;
      int r = ii >> 4, sg = (ii & 15) * 8;
      *(u32x4*)&Vls[r * 136 + sg] = *(const u32x4*)&Vg[(size_t)r * 4096 + kb + sg];
    }
    __syncthreads();

    f32x4 s[4][2][2];
#pragma unroll
    for (int g = 0; g < 4; ++g)
#pragma unroll
      for (int t = 0; t < 2; ++t) {
        int tb = ((g << 1) | t) << 10;
        bf16x8 alo = __builtin_bit_cast(bf16x8, *(const u32x4*)&Kls[tb + krd[0]]);
        bf16x8 ahi = __builtin_bit_cast(bf16x8, *(const u32x4*)&Kls[tb + krd[1]]);
#pragma unroll
        for (int qt = 0; qt < 2; ++qt) {
          f32x4 z = {};
          z = __builtin_amdgcn_mfma_f32_16x16x32_bf16(alo, qf[qt][0], z, 0, 0, 0);
          z = __builtin_amdgcn_mfma_f32_16x16x32_bf16(ahi, qf[qt][1], z, 0, 0, 0);
          s[g][t][qt] = z;
        }
      }

#pragma unroll
    for (int qt = 0; qt < 2; ++qt) {
      if (kb + 127 > qbase + wave * 32 + qt * 16) {
#pragma unroll
        for (int g = 0; g < 4; ++g)
#pragma unroll
          for (int t = 0; t < 2; ++t)
#pragma unroll
            for (int r = 0; r < 4; ++r) {
              int key = kb + 32 * g + 8 * lgrp + 4 * t + r;
              if (key > qrow[qt]) s[g][t][qt][r] = -3e38f;
            }
      }
    }

#pragma unroll
    for (int qt = 0; qt < 2; ++qt) {
      f32x4 v0 = s[0][0][qt], v1 = s[0][1][qt];
#pragma unroll
      for (int g = 1; g < 4; ++g)
#pragma unroll
        for (int r = 0; r < 4; ++r) {
          v0[r] = fmaxf(v0[r], s[g][0][qt][r]);
          v1[r] = fmaxf(v1[r], s[g][1][qt][r]);
        }
      float mx = fmaxf(fmaxf(fmaxf(v0[0], v0[1]), fmaxf(v0[2], v0[3])),
                       fmaxf(fmaxf(v1[0], v1[1]), fmaxf(v1[2], v1[3])));
      mx = fmaxf(mx, __shfl_xor(mx, 16, 64));
      mx = fmaxf(mx, __shfl_xor(mx, 32, 64));
      float mnew = fmaxf(m_i[qt], mx);
      float alpha = __builtin_amdgcn_exp2f(m_i[qt] - mnew);
      m_i[qt] = mnew;
      f32x4 su = {};
#pragma unroll
      for (int g = 0; g < 4; ++g)
#pragma unroll
        for (int t = 0; t < 2; ++t)
#pragma unroll
          for (int r = 0; r < 4; ++r) {
            float ev = __builtin_amdgcn_exp2f(s[g][t][qt][r] - mnew);
            s[g][t][qt][r] = ev;
            su[r] += ev;
          }
      float rs = (su[0] + su[1]) + (su[2] + su[3]);
      rs += __shfl_xor(rs, 16, 64);
      rs += __shfl_xor(rs, 32, 64);
      l_i[qt] = l_i[qt] * alpha + rs;
#pragma unroll
      for (int dt = 0; dt < 4; ++dt)
#pragma unroll
        for (int r = 0; r < 4; ++r) accO[qt][dt][r] *= alpha;
    }

#pragma unroll
    for (int g = 0; g < 4; ++g) {
      bf16x8 pf[2];
#pragma unroll
      for (int qt = 0; qt < 2; ++qt) {
        u32x4 pk;
        pk[0] = packtr(s[g][0][qt][0], s[g][0][qt][1]);
        pk[1] = packtr(s[g][0][qt][2], s[g][0][qt][3]);
        pk[2] = packtr(s[g][1][qt][0], s[g][1][qt][1]);
        pk[3] = packtr(s[g][1][qt][2], s[g][1][qt][3]);
        pf[qt] = __builtin_bit_cast(bf16x8, pk);
      }
#pragma unroll
      for (int dt = 0; dt < 4; ++dt) {
        bf16x8 vf = __builtin_bit_cast(bf16x8, *(const u32x4*)&Vls[vbase + dt * 2176 + 32 * g]);
        accO[0][dt] = __builtin_amdgcn_mfma_f32_16x16x32_bf16(vf, pf[0], accO[0][dt], 0, 0, 0);
        accO[1][dt] = __builtin_amdgcn_mfma_f32_16x16x32_bf16(vf, pf[1], accO[1][dt], 0, 0, 0);
      }
    }
  }

#pragma unroll
  for (int qt = 0; qt < 2; ++qt) {
    float inv = 1.f / l_i[qt];
#pragma unroll
    for (int dt = 0; dt < 4; ++dt) {
      uint2 o;
      o.x = pack2bf(accO[qt][dt][0] * inv, accO[qt][dt][1] * inv);
      o.y = pack2bf(accO[qt][dt][2] * inv, accO[qt][dt][3] * inv);
      *(uint2*)&ctx[(size_t)qrow[qt] * 1024 + head * 64 + dt * 16 + lgrp * 4] = o;
    }
  }
}

extern "C" void kernel_launch(void* const* d_in, const int* in_sizes, int n_in,
                              void* d_out, int out_size, void* d_ws, size_t ws_size,
                              hipStream_t stream) {
  const float* x    = (const float*)d_in[0];
  const float* wq   = (const float*)d_in[3];
  const float* wk   = (const float*)d_in[4];
  const float* wv   = (const float*)d_in[5];
  const float* wo   = (const float*)d_in[6];
  const float* sinT = (const float*)d_in[7];
  const float* cosT = (const float*)d_in[8];

  unsigned short* ws    = (unsigned short*)d_ws;
  unsigned short* xb    = ws;                          // 4096*1024
  unsigned short* wtqkv = xb + 4096 * 1024;            // 1536*1024
  unsigned short* wot   = wtqkv + 1536 * 1024;         // 1024*1024
  unsigned short* Qh    = wot + 1024 * 1024;           // 16*4096*64
  unsigned short* Kh    = Qh + 16 * 4096 * 64;         // 4*4096*64
  unsigned short* Vt    = Kh + 4 * 4096 * 64;          // 4*64*4096
  unsigned short* ctx   = Vt + 4 * 64 * 4096;          // 4096*1024
  float* out = (float*)d_out;

  prep<<<6656, 256, 0, stream>>>(x, wq, wk, wv, wo, xb, wtqkv, wot);
  gemm_qkv<<<dim3(12, 32), 256, 0, stream>>>(xb, wtqkv, sinT, cosT, Qh, Kh, Vt);
  attn5<<<dim3(512), 256, 0, stream>>>(Qh, Kh, Vt, ctx);
  gemm_out<<<dim3(8, 32), 256, 0, stream>>>(ctx, wot, out);
}

// Round 8
// 250.017 us; speedup vs baseline: 1.2206x; 1.0038x over previous
//
#include <hip/hip_runtime.h>

typedef __bf16 bf16x8 __attribute__((ext_vector_type(8)));
typedef float f32x4 __attribute__((ext_vector_type(4)));
typedef unsigned int u32x4 __attribute__((ext_vector_type(4)));

typedef const void __attribute__((address_space(1)))* gas1;
typedef void __attribute__((address_space(3)))* las3;

__device__ __forceinline__ unsigned short f2bf(float f) {
  unsigned int u = __builtin_bit_cast(unsigned int, f);
  u += 0x7fffu + ((u >> 16) & 1u);   // RNE
  return (unsigned short)(u >> 16);
}
__device__ __forceinline__ float bf2f(unsigned short h) {
  unsigned int u = ((unsigned int)h) << 16;
  return __builtin_bit_cast(float, u);
}
__device__ __forceinline__ unsigned int pack2bf(float lo, float hi) {
  return (unsigned int)f2bf(lo) | ((unsigned int)f2bf(hi) << 16);
}
// truncating pack (P in [0,1])
__device__ __forceinline__ unsigned int packtr(float lo, float hi) {
  return __builtin_amdgcn_perm(__builtin_bit_cast(unsigned int, hi),
                               __builtin_bit_cast(unsigned int, lo), 0x07060302u);
}

// ---------------- fused prep: x->bf16 + 4 weight transposes ----------------
__global__ __launch_bounds__(256) void prep(const float* __restrict__ x,
                                            const float* __restrict__ wq,
                                            const float* __restrict__ wk,
                                            const float* __restrict__ wv,
                                            const float* __restrict__ wo,
                                            unsigned short* __restrict__ xb,
                                            unsigned short* __restrict__ wtqkv,
                                            unsigned short* __restrict__ wot) {
  __shared__ float tile[32][33];
  const int b = blockIdx.x;
  const int tid = threadIdx.x;
  if (b < 4096) {
    int i = b * 256 + tid;
    float4 v = ((const float4*)x)[i];
    uint2 o;
    o.x = pack2bf(v.x, v.y);
    o.y = pack2bf(v.z, v.w);
    ((uint2*)xb)[i] = o;
    return;
  }
  const float* src;
  unsigned short* dst;
  int R, C, t;
  if (b < 5120)      { t = b - 4096; src = wq; dst = wtqkv;               R = 1024; C = 1024; }
  else if (b < 5376) { t = b - 5120; src = wk; dst = wtqkv + 1024 * 1024; R = 1024; C = 256; }
  else if (b < 5632) { t = b - 5376; src = wv; dst = wtqkv + 1280 * 1024; R = 1024; C = 256; }
  else               { t = b - 5632; src = wo; dst = wot;                 R = 1024; C = 1024; }
  const int ntc = C >> 5;
  const int c0 = (t % ntc) * 32, r0 = (t / ntc) * 32;
  const int tx = tid & 31, ty = tid >> 5;
#pragma unroll
  for (int i = 0; i < 4; ++i)
    tile[ty + i * 8][tx] = src[(r0 + ty + i * 8) * C + c0 + tx];
  __syncthreads();
#pragma unroll
  for (int i = 0; i < 4; ++i)
    dst[(c0 + ty + i * 8) * R + r0 + tx] = f2bf(tile[tx][ty + i * 8]);
}

// ---------------- QKV GEMM: rolling single-barrier dbuf + RoPE/split/V^T epilogue -----
__global__ __launch_bounds__(256, 2) void gemm_qkv(const unsigned short* __restrict__ A,
                                                   const unsigned short* __restrict__ Bt,
                                                   const float* __restrict__ sinT,
                                                   const float* __restrict__ cosT,
                                                   unsigned short* __restrict__ Qh,
                                                   unsigned short* __restrict__ Kh,
                                                   unsigned short* __restrict__ Vt) {
  __shared__ __align__(16) unsigned short Als[2][128 * 32];
  __shared__ __align__(16) unsigned short Bls[2][128 * 32];
  const int K = 1024;
  const int tid = threadIdx.x;
  const int wave = tid >> 6, lane = tid & 63;
  const int lgrp = lane >> 4, lmod = lane & 15;
  const int wm = (wave & 1) * 64, wn = (wave >> 1) * 64;
  const int m0 = blockIdx.y * 128, n0 = blockIdx.x * 128;
  const int rr0 = tid >> 2, cc0 = (tid & 3) * 8;
  const int rr1 = (tid + 256) >> 2, cc1 = cc0;

  f32x4 acc[4][4] = {};

  // preload k0=0 into buf 0
  __builtin_amdgcn_global_load_lds((gas1)(const void*)&A[(size_t)(m0 + rr0) * K + cc0],
                                   (las3)(void*)&Als[0][(wave * 64) * 8], 16, 0, 0);
  __builtin_amdgcn_global_load_lds((gas1)(const void*)&Bt[(size_t)(n0 + rr0) * K + cc0],
                                   (las3)(void*)&Bls[0][(wave * 64) * 8], 16, 0, 0);
  __builtin_amdgcn_global_load_lds((gas1)(const void*)&A[(size_t)(m0 + rr1) * K + cc1],
                                   (las3)(void*)&Als[0][(256 + wave * 64) * 8], 16, 0, 0);
  __builtin_amdgcn_global_load_lds((gas1)(const void*)&Bt[(size_t)(n0 + rr1) * K + cc1],
                                   (las3)(void*)&Bls[0][(256 + wave * 64) * 8], 16, 0, 0);
  __syncthreads();

  int p = 0;
  for (int k0 = 0; k0 < K; k0 += 32, p ^= 1) {
    if (k0 + 32 < K) {
      int kk = k0 + 32;
      __builtin_amdgcn_global_load_lds((gas1)(const void*)&A[(size_t)(m0 + rr0) * K + kk + cc0],
                                       (las3)(void*)&Als[p ^ 1][(wave * 64) * 8], 16, 0, 0);
      __builtin_amdgcn_global_load_lds((gas1)(const void*)&Bt[(size_t)(n0 + rr0) * K + kk + cc0],
                                       (las3)(void*)&Bls[p ^ 1][(wave * 64) * 8], 16, 0, 0);
      __builtin_amdgcn_global_load_lds((gas1)(const void*)&A[(size_t)(m0 + rr1) * K + kk + cc1],
                                       (las3)(void*)&Als[p ^ 1][(256 + wave * 64) * 8], 16, 0, 0);
      __builtin_amdgcn_global_load_lds((gas1)(const void*)&Bt[(size_t)(n0 + rr1) * K + kk + cc1],
                                       (las3)(void*)&Bls[p ^ 1][(256 + wave * 64) * 8], 16, 0, 0);
    }
    bf16x8 af[4], bfr[4];
#pragma unroll
    for (int mi = 0; mi < 4; ++mi)
      af[mi] = __builtin_bit_cast(bf16x8, *(const u32x4*)&Als[p][(wm + mi * 16 + lmod) * 32 + lgrp * 8]);
#pragma unroll
    for (int ni = 0; ni < 4; ++ni)
      bfr[ni] = __builtin_bit_cast(bf16x8, *(const u32x4*)&Bls[p][(wn + ni * 16 + lmod) * 32 + lgrp * 8]);
#pragma unroll
    for (int mi = 0; mi < 4; ++mi)
#pragma unroll
      for (int ni = 0; ni < 4; ++ni)
        acc[mi][ni] = __builtin_amdgcn_mfma_f32_16x16x32_bf16(af[mi], bfr[ni], acc[mi][ni], 0, 0, 0);
    __syncthreads();
  }

  const int cbase = n0 + wn;           // multiple of 64
  if (cbase >= 1280) {
    const int kvh = (cbase - 1280) >> 6;
#pragma unroll
    for (int mi = 0; mi < 4; ++mi)
#pragma unroll
      for (int ni = 0; ni < 4; ++ni) {
        int d = ni * 16 + lmod;
        int s = m0 + wm + mi * 16 + lgrp * 4;
        uint2 o;
        o.x = pack2bf(acc[mi][ni][0], acc[mi][ni][1]);
        o.y = pack2bf(acc[mi][ni][2], acc[mi][ni][3]);
        *(uint2*)&Vt[((size_t)(kvh * 64 + d)) * 4096 + s] = o;
      }
    return;
  }

  // Q/K: rope; stage sin/cos into dead LDS
  float* sinls = (float*)&Als[0][0];   // 16 KB
  float* cosls = (float*)&Bls[0][0];
#pragma unroll
  for (int j = 0; j < 4; ++j) {
    int idx = tid + j * 256;
    int rr = idx >> 3, cc = (idx & 7) * 4;
    *(float4*)&sinls[rr * 32 + cc] = *(const float4*)&sinT[(size_t)(m0 + rr) * 32 + cc];
    *(float4*)&cosls[rr * 32 + cc] = *(const float4*)&cosT[(size_t)(m0 + rr) * 32 + cc];
  }
  __syncthreads();

  const float qscale = 0.18033688011112042f;   // 0.125 * log2(e)
  const bool isQ = (cbase < 1024);
  const int h = isQ ? (cbase >> 6) : ((cbase - 1024) >> 6);
  unsigned short* dstbase = isQ ? Qh : Kh;
  const bool evn = (lmod & 1) == 0;
#pragma unroll
  for (int mi = 0; mi < 4; ++mi)
#pragma unroll
    for (int ni = 0; ni < 4; ++ni) {
      int d = ni * 16 + lmod;
      int i = ni * 8 + (lmod >> 1);
#pragma unroll
      for (int r = 0; r < 4; ++r) {
        float v = acc[mi][ni][r];
        float pp = __shfl_xor(v, 1, 64);
        int rl = wm + mi * 16 + lgrp * 4 + r;
        float sn = sinls[rl * 32 + i], cs = cosls[rl * 32 + i];
        float e = evn ? v : pp, o = evn ? pp : v;
        float outv = evn ? (cs * e - sn * o) : (sn * e + cs * o);
        if (isQ) outv *= qscale;
        dstbase[((size_t)h * 4096 + m0 + rl) * 64 + d] = f2bf(outv);
      }
    }
}

// ---------------- out-proj GEMM: rolling single-barrier dbuf, f32 out ----------------
__global__ __launch_bounds__(256, 2) void gemm_out(const unsigned short* __restrict__ A,
                                                   const unsigned short* __restrict__ Bt,
                                                   float* __restrict__ Cout) {
  __shared__ __align__(16) unsigned short Als[2][128 * 32];
  __shared__ __align__(16) unsigned short Bls[2][128 * 32];
  const int K = 1024, N = 1024;
  const int tid = threadIdx.x;
  const int wave = tid >> 6, lane = tid & 63;
  const int lgrp = lane >> 4, lmod = lane & 15;
  const int wm = (wave & 1) * 64, wn = (wave >> 1) * 64;
  const int m0 = blockIdx.y * 128, n0 = blockIdx.x * 128;
  const int rr0 = tid >> 2, cc0 = (tid & 3) * 8;
  const int rr1 = (tid + 256) >> 2, cc1 = cc0;

  f32x4 acc[4][4] = {};

  __builtin_amdgcn_global_load_lds((gas1)(const void*)&A[(size_t)(m0 + rr0) * K + cc0],
                                   (las3)(void*)&Als[0][(wave * 64) * 8], 16, 0, 0);
  __builtin_amdgcn_global_load_lds((gas1)(const void*)&Bt[(size_t)(n0 + rr0) * K + cc0],
                                   (las3)(void*)&Bls[0][(wave * 64) * 8], 16, 0, 0);
  __builtin_amdgcn_global_load_lds((gas1)(const void*)&A[(size_t)(m0 + rr1) * K + cc1],
                                   (las3)(void*)&Als[0][(256 + wave * 64) * 8], 16, 0, 0);
  __builtin_amdgcn_global_load_lds((gas1)(const void*)&Bt[(size_t)(n0 + rr1) * K + cc1],
                                   (las3)(void*)&Bls[0][(256 + wave * 64) * 8], 16, 0, 0);
  __syncthreads();

  int p = 0;
  for (int k0 = 0; k0 < K; k0 += 32, p ^= 1) {
    if (k0 + 32 < K) {
      int kk = k0 + 32;
      __builtin_amdgcn_global_load_lds((gas1)(const void*)&A[(size_t)(m0 + rr0) * K + kk + cc0],
                                       (las3)(void*)&Als[p ^ 1][(wave * 64) * 8], 16, 0, 0);
      __builtin_amdgcn_global_load_lds((gas1)(const void*)&Bt[(size_t)(n0 + rr0) * K + kk + cc0],
                                       (las3)(void*)&Bls[p ^ 1][(wave * 64) * 8], 16, 0, 0);
      __builtin_amdgcn_global_load_lds((gas1)(const void*)&A[(size_t)(m0 + rr1) * K + kk + cc1],
                                       (las3)(void*)&Als[p ^ 1][(256 + wave * 64) * 8], 16, 0, 0);
      __builtin_amdgcn_global_load_lds((gas1)(const void*)&Bt[(size_t)(n0 + rr1) * K + kk + cc1],
                                       (las3)(void*)&Bls[p ^ 1][(256 + wave * 64) * 8], 16, 0, 0);
    }
    bf16x8 af[4], bfr[4];
#pragma unroll
    for (int mi = 0; mi < 4; ++mi)
      af[mi] = __builtin_bit_cast(bf16x8, *(const u32x4*)&Als[p][(wm + mi * 16 + lmod) * 32 + lgrp * 8]);
#pragma unroll
    for (int ni = 0; ni < 4; ++ni)
      bfr[ni] = __builtin_bit_cast(bf16x8, *(const u32x4*)&Bls[p][(wn + ni * 16 + lmod) * 32 + lgrp * 8]);
#pragma unroll
    for (int mi = 0; mi < 4; ++mi)
#pragma unroll
      for (int ni = 0; ni < 4; ++ni)
        acc[mi][ni] = __builtin_amdgcn_mfma_f32_16x16x32_bf16(af[mi], bfr[ni], acc[mi][ni], 0, 0, 0);
    __syncthreads();
  }

#pragma unroll
  for (int mi = 0; mi < 4; ++mi)
#pragma unroll
    for (int ni = 0; ni < 4; ++ni)
#pragma unroll
      for (int r = 0; r < 4; ++r) {
        int row = m0 + wm + mi * 16 + lgrp * 4 + r;
        int col = n0 + wn + ni * 16 + lmod;
        Cout[(size_t)row * N + col] = acc[mi][ni][r];
      }
}

// ---------------- Flash attention: attn3 layout + double-buffered chunks ----------------
// One barrier per chunk: prefetch chunk kc+1 (global->VGPR) during compute of kc,
// ds_write into alternate buffers at loop end.
__global__ __launch_bounds__(256, 2) void attn6(const unsigned short* __restrict__ Qh,
                                                const unsigned short* __restrict__ Kh,
                                                const unsigned short* __restrict__ Vt,
                                                unsigned short* __restrict__ ctx) {
  __shared__ __align__(16) unsigned short Kls[2][128 * 68];   // [key][d], stride 68
  __shared__ __align__(16) unsigned short Vls[2][64 * 136];   // [d][key], stride 136
  const int bx = blockIdx.x;
  const int head = bx & 15;
  const int qidx = bx >> 4;
  const int qb = (qidx < 16) ? (31 - qidx) : (qidx - 16);
  const int kvh = head >> 2;
  const int tid = threadIdx.x;
  const int wave = tid >> 6, lane = tid & 63;
  const int lgrp = lane >> 4, lmod = lane & 15;
  const int qbase = qb * 128;

  const unsigned short* Kg = Kh + (size_t)kvh * 4096 * 64;
  const unsigned short* Vg = Vt + (size_t)kvh * 64 * 4096;

  bf16x8 qf[2][2];
  int qrow[2];
#pragma unroll
  for (int qt = 0; qt < 2; ++qt) {
    qrow[qt] = qbase + wave * 32 + qt * 16 + lmod;
    const unsigned short* Qg = Qh + ((size_t)head * 4096 + qrow[qt]) * 64;
    qf[qt][0] = __builtin_bit_cast(bf16x8, *(const u32x4*)&Qg[lgrp * 8]);
    qf[qt][1] = __builtin_bit_cast(bf16x8, *(const u32x4*)&Qg[32 + lgrp * 8]);
  }

  const int kbase = (8 * (lmod >> 2) + (lmod & 3)) * 68 + lgrp * 8;
  const int vbase = lmod * 136 + lgrp * 8;

  // staging geometry
  const int kr = tid >> 3, ks = (tid & 7) * 8;      // K: rows 0..127 over 4 iters? (tid covers 0..255 -> 32 rows/iter via +i*256)
  const int vr = tid >> 4, vs = (tid & 15) * 8;

  f32x4 accO[2][4] = {};
  float m_i[2] = {-3e38f, -3e38f}, l_i[2] = {0.f, 0.f};

  u32x4 kreg[4], vreg[4];
  // preload chunk 0
#pragma unroll
  for (int i = 0; i < 4; ++i) {
    int ii = tid + i * 256;
    kreg[i] = *(const u32x4*)&Kg[(size_t)(ii >> 3) * 64 + (ii & 7) * 8];
    vreg[i] = *(const u32x4*)&Vg[(size_t)(ii >> 4) * 4096 + (ii & 15) * 8];
  }
#pragma unroll
  for (int i = 0; i < 4; ++i) {
    int ii = tid + i * 256;
    uint2* pd = (uint2*)&Kls[0][(ii >> 3) * 68 + (ii & 7) * 8];
    pd[0] = make_uint2(kreg[i][0], kreg[i][1]);
    pd[1] = make_uint2(kreg[i][2], kreg[i][3]);
    *(u32x4*)&Vls[0][(ii >> 4) * 136 + (ii & 15) * 8] = vreg[i];
  }
  __syncthreads();

  int p = 0;
  for (int kc = 0; kc <= qb; ++kc, p ^= 1) {
    const int kb = kc * 128;
    const bool hasNext = (kc < qb);
    if (hasNext) {
      const int nb = kb + 128;
#pragma unroll
      for (int i = 0; i < 4; ++i) {
        int ii = tid + i * 256;
        kreg[i] = *(const u32x4*)&Kg[(size_t)(nb + (ii >> 3)) * 64 + (ii & 7) * 8];
        vreg[i] = *(const u32x4*)&Vg[(size_t)(ii >> 4) * 4096 + nb + (ii & 15) * 8];
      }
    }

    f32x4 s[4][2][2];
#pragma unroll
    for (int g = 0; g < 4; ++g)
#pragma unroll
      for (int t = 0; t < 2; ++t) {
        const unsigned short* ka = &Kls[p][kbase + (32 * g + 4 * t) * 68];
        uint2 a0 = *(const uint2*)&ka[0];
        uint2 a1 = *(const uint2*)&ka[4];
        uint2 b0 = *(const uint2*)&ka[32];
        uint2 b1 = *(const uint2*)&ka[36];
        u32x4 lo = {a0.x, a0.y, a1.x, a1.y};
        u32x4 hi = {b0.x, b0.y, b1.x, b1.y};
        bf16x8 alo = __builtin_bit_cast(bf16x8, lo);
        bf16x8 ahi = __builtin_bit_cast(bf16x8, hi);
#pragma unroll
        for (int qt = 0; qt < 2; ++qt) {
          f32x4 z = {};
          z = __builtin_amdgcn_mfma_f32_16x16x32_bf16(alo, qf[qt][0], z, 0, 0, 0);
          z = __builtin_amdgcn_mfma_f32_16x16x32_bf16(ahi, qf[qt][1], z, 0, 0, 0);
          s[g][t][qt] = z;
        }
      }

#pragma unroll
    for (int qt = 0; qt < 2; ++qt) {
      if (kb + 127 > qbase + wave * 32 + qt * 16) {
#pragma unroll
        for (int g = 0; g < 4; ++g)
#pragma unroll
          for (int t = 0; t < 2; ++t)
#pragma unroll
            for (int r = 0; r < 4; ++r) {
              int key = kb + 32 * g + 8 * lgrp + 4 * t + r;
              if (key > qrow[qt]) s[g][t][qt][r] = -3e38f;
            }
      }
    }

#pragma unroll
    for (int qt = 0; qt < 2; ++qt) {
      f32x4 v0 = s[0][0][qt], v1 = s[0][1][qt];
#pragma unroll
      for (int g = 1; g < 4; ++g)
#pragma unroll
        for (int r = 0; r < 4; ++r) {
          v0[r] = fmaxf(v0[r], s[g][0][qt][r]);
          v1[r] = fmaxf(v1[r], s[g][1][qt][r]);
        }
      float mx = fmaxf(fmaxf(fmaxf(v0[0], v0[1]), fmaxf(v0[2], v0[3])),
                       fmaxf(fmaxf(v1[0], v1[1]), fmaxf(v1[2], v1[3])));
      mx = fmaxf(mx, __shfl_xor(mx, 16, 64));
      mx = fmaxf(mx, __shfl_xor(mx, 32, 64));
      float mnew = fmaxf(m_i[qt], mx);
      float alpha = __builtin_amdgcn_exp2f(m_i[qt] - mnew);
      m_i[qt] = mnew;
      f32x4 su = {};
#pragma unroll
      for (int g = 0; g < 4; ++g)
#pragma unroll
        for (int t = 0; t < 2; ++t)
#pragma unroll
          for (int r = 0; r < 4; ++r) {
            float ev = __builtin_amdgcn_exp2f(s[g][t][qt][r] - mnew);
            s[g][t][qt][r] = ev;
            su[r] += ev;
          }
      float rs = (su[0] + su[1]) + (su[2] + su[3]);
      rs += __shfl_xor(rs, 16, 64);
      rs += __shfl_xor(rs, 32, 64);
      l_i[qt] = l_i[qt] * alpha + rs;
#pragma unroll
      for (int dt = 0; dt < 4; ++dt)
#pragma unroll
        for (int r = 0; r < 4; ++r) accO[qt][dt][r] *= alpha;
    }

#pragma unroll
    for (int g = 0; g < 4; ++g) {
      bf16x8 pf[2];
#pragma unroll
      for (int qt = 0; qt < 2; ++qt) {
        u32x4 pk;
        pk[0] = packtr(s[g][0][qt][0], s[g][0][qt][1]);
        pk[1] = packtr(s[g][0][qt][2], s[g][0][qt][3]);
        pk[2] = packtr(s[g][1][qt][0], s[g][1][qt][1]);
        pk[3] = packtr(s[g][1][qt][2], s[g][1][qt][3]);
        pf[qt] = __builtin_bit_cast(bf16x8, pk);
      }
#pragma unroll
      for (int dt = 0; dt < 4; ++dt) {
        bf16x8 vf = __builtin_bit_cast(bf16x8, *(const u32x4*)&Vls[p][vbase + dt * 2176 + 32 * g]);
        accO[0][dt] = __builtin_amdgcn_mfma_f32_16x16x32_bf16(vf, pf[0], accO[0][dt], 0, 0, 0);
        accO[1][dt] = __builtin_amdgcn_mfma_f32_16x16x32_bf16(vf, pf[1], accO[1][dt], 0, 0, 0);
      }
    }

    if (hasNext) {
#pragma unroll
      for (int i = 0; i < 4; ++i) {
        int ii = tid + i * 256;
        uint2* pd = (uint2*)&Kls[p ^ 1][(ii >> 3) * 68 + (ii & 7) * 8];
        pd[0] = make_uint2(kreg[i][0], kreg[i][1]);
        pd[1] = make_uint2(kreg[i][2], kreg[i][3]);
        *(u32x4*)&Vls[p ^ 1][(ii >> 4) * 136 + (ii & 15) * 8] = vreg[i];
      }
    }
    __syncthreads();
  }

#pragma unroll
  for (int qt = 0; qt < 2; ++qt) {
    float inv = 1.f / l_i[qt];
#pragma unroll
    for (int dt = 0; dt < 4; ++dt) {
      uint2 o;
      o.x = pack2bf(accO[qt][dt][0] * inv, accO[qt][dt][1] * inv);
      o.y = pack2bf(accO[qt][dt][2] * inv, accO[qt][dt][3] * inv);
      *(uint2*)&ctx[(size_t)qrow[qt] * 1024 + head * 64 + dt * 16 + lgrp * 4] = o;
    }
  }
}

extern "C" void kernel_launch(void* const* d_in, const int* in_sizes, int n_in,
                              void* d_out, int out_size, void* d_ws, size_t ws_size,
                              hipStream_t stream) {
  const float* x    = (const float*)d_in[0];
  const float* wq   = (const float*)d_in[3];
  const float* wk   = (const float*)d_in[4];
  const float* wv   = (const float*)d_in[5];
  const float* wo   = (const float*)d_in[6];
  const float* sinT = (const float*)d_in[7];
  const float* cosT = (const float*)d_in[8];

  unsigned short* ws    = (unsigned short*)d_ws;
  unsigned short* xb    = ws;                          // 4096*1024
  unsigned short* wtqkv = xb + 4096 * 1024;            // 1536*1024
  unsigned short* wot   = wtqkv + 1536 * 1024;         // 1024*1024
  unsigned short* Qh    = wot + 1024 * 1024;           // 16*4096*64
  unsigned short* Kh    = Qh + 16 * 4096 * 64;         // 4*4096*64
  unsigned short* Vt    = Kh + 4 * 4096 * 64;          // 4*64*4096
  unsigned short* ctx   = Vt + 4 * 64 * 4096;          // 4096*1024
  float* out = (float*)d_out;

  prep<<<6656, 256, 0, stream>>>(x, wq, wk, wv, wo, xb, wtqkv, wot);
  gemm_qkv<<<dim3(12, 32), 256, 0, stream>>>(xb, wtqkv, sinT, cosT, Qh, Kh, Vt);
  attn6<<<dim3(512), 256, 0, stream>>>(Qh, Kh, Vt, ctx);
  gemm_out<<<dim3(8, 32), 256, 0, stream>>>(ctx, wot, out);
}